// Round 1
// baseline (6208.638 us; speedup 1.0000x reference)
//
#include <hip/hip_runtime.h>
#include <math.h>

#define N_NODES 100000
#define NE      1600000
#define T_STEPS 8

__device__ __forceinline__ float sigmoid_f(float x) { return 1.f / (1.f + __expf(-x)); }
__device__ __forceinline__ float tanh_f(float x) {
  float e = __expf(2.f * x);
  return 1.f - 2.f / (e + 1.f);
}

// ---------------- per-snapshot CSR build ----------------

__global__ void k_init(int* __restrict__ cnt, float* __restrict__ degv) {
  int i = blockIdx.x * 256 + threadIdx.x;
  if (i < N_NODES) { cnt[i] = 0; degv[i] = 1.0f; }  // deg starts at 1 (self loop w=1)
}

__global__ void k_hist(const int* __restrict__ dst, const float* __restrict__ ew,
                       int* __restrict__ cnt, float* __restrict__ degv) {
  int e = blockIdx.x * 256 + threadIdx.x;
  if (e < NE) {
    int d = dst[e];
    atomicAdd(&cnt[d], 1);
    atomicAdd(&degv[d], ew[e]);
  }
}

__global__ void k_dinv(float* __restrict__ degv) {
  int i = blockIdx.x * 256 + threadIdx.x;
  if (i < N_NODES) degv[i] = rsqrtf(degv[i]);  // deg >= 1 always
}

// chunk = 2048 per block (256 thr x 8). Writes per-chunk exclusive scan, chunk totals to sums.
__global__ void k_scan_a(const int* __restrict__ cnt, int* __restrict__ rp, int* __restrict__ sums) {
  __shared__ int sdata[256];
  int tid = threadIdx.x;
  int base = blockIdx.x * 2048 + tid * 8;
  int v[8];
  int tot = 0;
#pragma unroll
  for (int i = 0; i < 8; ++i) {
    int idx = base + i;
    int c = (idx < N_NODES) ? cnt[idx] : 0;
    v[i] = tot; tot += c;
  }
  sdata[tid] = tot;
  __syncthreads();
  for (int off = 1; off < 256; off <<= 1) {
    int x = (tid >= off) ? sdata[tid - off] : 0;
    __syncthreads();
    sdata[tid] += x;
    __syncthreads();
  }
  int texcl = sdata[tid] - tot;  // exclusive prefix of this thread within chunk
  if (tid == 255) sums[blockIdx.x] = sdata[255];
#pragma unroll
  for (int i = 0; i < 8; ++i) {
    int idx = base + i;
    if (idx < N_NODES) rp[idx] = texcl + v[i];
  }
}

// add chunk bases (computed by summing sums[0..cid-1], only 49 entries), fill cursor.
__global__ void k_scan_c(int* __restrict__ rp, const int* __restrict__ sums, int* __restrict__ cur) {
  __shared__ int sbase;
  int tid = threadIdx.x;
  int cid = blockIdx.x >> 3;  // 256-thread block sits inside one 2048 chunk
  if (tid == 0) {
    int b = 0;
    for (int c = 0; c < cid; ++c) b += sums[c];
    sbase = b;
  }
  __syncthreads();
  int idx = blockIdx.x * 256 + tid;
  if (idx < N_NODES) {
    int vv = rp[idx] + sbase;
    rp[idx] = vv;
    cur[idx] = vv;
  }
  if (blockIdx.x == 0 && tid == 0) rp[N_NODES] = NE;
}

__global__ void k_place(const int* __restrict__ src, const int* __restrict__ dst,
                        const float* __restrict__ ew, const float* __restrict__ dinv,
                        int* __restrict__ cur, int* __restrict__ srcs, float* __restrict__ nw) {
  int e = blockIdx.x * 256 + threadIdx.x;
  if (e < NE) {
    int s = src[e], d = dst[e];
    float w = ew[e];
    int p = atomicAdd(&cur[d], 1);
    srcs[p] = s;
    nw[p] = dinv[s] * w * dinv[d];
  }
}

// ---------------- GCN propagation: one wave per node, lane = feature ----------------

__global__ void k_prop(const float* __restrict__ hin, const int* __restrict__ rp,
                       const int* __restrict__ srcs, const float* __restrict__ nw,
                       const float* __restrict__ dinv, const float* __restrict__ bias,
                       float* __restrict__ hout, int mode /*0=relu, 1=tanh*/) {
  int node = blockIdx.x * 4 + (threadIdx.x >> 6);
  int f = threadIdx.x & 63;
  float di = dinv[node];
  float acc = hin[(size_t)node * 64 + f] * di * di;  // self loop: norm = dinv^2
  int e0 = rp[node], e1 = rp[node + 1];
  float a0 = 0.f, a1 = 0.f, a2 = 0.f, a3 = 0.f;
  int j = e0;
  for (; j + 4 <= e1; j += 4) {
    int s0 = srcs[j], s1 = srcs[j + 1], s2 = srcs[j + 2], s3 = srcs[j + 3];
    float w0 = nw[j], w1 = nw[j + 1], w2 = nw[j + 2], w3 = nw[j + 3];
    a0 = fmaf(hin[(size_t)s0 * 64 + f], w0, a0);
    a1 = fmaf(hin[(size_t)s1 * 64 + f], w1, a1);
    a2 = fmaf(hin[(size_t)s2 * 64 + f], w2, a2);
    a3 = fmaf(hin[(size_t)s3 * 64 + f], w3, a3);
  }
  for (; j < e1; ++j) acc = fmaf(hin[(size_t)srcs[j] * 64 + f], nw[j], acc);
  acc += (a0 + a1) + (a2 + a3);
  acc += bias[f];
  hout[(size_t)node * 64 + f] = (mode == 0) ? fmaxf(acc, 0.f) : tanh_f(acc);
}

// ---------------- dense matmuls ----------------

// xw1 = x @ W1 : [N,128]@[128,64]
__global__ void k_xw1(const float* __restrict__ x, const float* __restrict__ W1, float* __restrict__ o) {
  __shared__ float sW[128 * 64];   // 32 KB
  __shared__ float sx[32 * 128];   // 16 KB
  int tid = threadIdx.x;
  int row0 = blockIdx.x * 32;
  for (int i = tid; i < 128 * 64; i += 256) sW[i] = W1[i];
  for (int i = tid; i < 32 * 128; i += 256) {
    int r = i >> 7, c = i & 127;
    sx[i] = x[(size_t)(row0 + r) * 128 + c];
  }
  __syncthreads();
  int f = tid & 63, w = tid >> 6;
  float acc[8];
#pragma unroll
  for (int m = 0; m < 8; ++m) acc[m] = 0.f;
  for (int k = 0; k < 128; ++k) {
    float wv = sW[k * 64 + f];
#pragma unroll
    for (int m = 0; m < 8; ++m)
      acc[m] = fmaf(sx[(w * 8 + m) * 128 + k], wv, acc[m]);
  }
#pragma unroll
  for (int m = 0; m < 8; ++m)
    o[(size_t)(row0 + w * 8 + m) * 64 + f] = acc[m];
}

// a = a @ W2 in place : [N,64]@[64,64] (rows staged to LDS first, so in-place is safe)
__global__ void k_mm64(float* __restrict__ a, const float* __restrict__ W2) {
  __shared__ float sW[64 * 64];   // 16 KB
  __shared__ float sx[32 * 64];   // 8 KB
  int tid = threadIdx.x;
  int row0 = blockIdx.x * 32;
  for (int i = tid; i < 64 * 64; i += 256) sW[i] = W2[i];
  for (int i = tid; i < 32 * 64; i += 256) {
    int r = i >> 6, c = i & 63;
    sx[i] = a[(size_t)(row0 + r) * 64 + c];
  }
  __syncthreads();
  int f = tid & 63, w = tid >> 6;
  float acc[8];
#pragma unroll
  for (int m = 0; m < 8; ++m) acc[m] = 0.f;
  for (int k = 0; k < 64; ++k) {
    float wv = sW[k * 64 + f];
#pragma unroll
    for (int m = 0; m < 8; ++m)
      acc[m] = fmaf(sx[(w * 8 + m) * 64 + k], wv, acc[m]);
  }
#pragma unroll
  for (int m = 0; m < 8; ++m)
    a[(size_t)(row0 + w * 8 + m) * 64 + f] = acc[m];
}

// ---------------- fused GRU step + output linear ----------------
// 512 threads = 8 waves x 8 nodes/wave. LDS < 64KB static => 2 blocks/CU.
__global__ __launch_bounds__(512) void k_gru(
    const float* __restrict__ gt, float* __restrict__ h,
    const float* __restrict__ Wih, const float* __restrict__ Whh,
    const float* __restrict__ bih, const float* __restrict__ bhh,
    const float* __restrict__ Wlin, const float* __restrict__ blin,
    float* __restrict__ outt, int first) {
  __shared__ float sW[2 * 16 * 192];  // 24576 B: k-tile of WihT | WhhT; reused for WlinT at end
  __shared__ float sx[64 * 64];       // 16384 B
  __shared__ float sh[64 * 64];       // 16384 B
  __shared__ float sbi[192];
  __shared__ float sbh[192];

  int tid = threadIdx.x;
  int node0 = blockIdx.x * 64;

  for (int i = tid; i < 192; i += 512) { sbi[i] = bih[i]; sbh[i] = bhh[i]; }
  for (int i = tid; i < 64 * 64; i += 512) {
    int m = i >> 6, k = i & 63;
    int n = node0 + m;
    sx[i] = (n < N_NODES) ? gt[(size_t)n * 64 + k] : 0.f;
    sh[i] = (first || n >= N_NODES) ? 0.f : h[(size_t)n * 64 + k];
  }
  __syncthreads();

  int f = tid & 63;
  int w = tid >> 6;
  int mb = w * 8;

  float air[8], aiz[8], ain[8], ahr[8], ahz[8], ahn[8];
#pragma unroll
  for (int m = 0; m < 8; ++m) {
    air[m] = sbi[f];      aiz[m] = sbi[64 + f];  ain[m] = sbi[128 + f];
    ahr[m] = sbh[f];      ahz[m] = sbh[64 + f];  ahn[m] = sbh[128 + f];
  }

  for (int kt = 0; kt < 64; kt += 16) {
    __syncthreads();  // previous tile reads complete before overwrite
    for (int i = tid; i < 16 * 192; i += 512) {
      int kk = i / 192, jj = i % 192;
      sW[i]        = Wih[jj * 64 + kt + kk];  // WihT[kk][jj]
      sW[3072 + i] = Whh[jj * 64 + kt + kk];
    }
    __syncthreads();
#pragma unroll
    for (int kk = 0; kk < 16; ++kk) {
      int k = kt + kk;
      float wr = sW[kk * 192 + f];
      float wz = sW[kk * 192 + 64 + f];
      float wn = sW[kk * 192 + 128 + f];
      float vr = sW[3072 + kk * 192 + f];
      float vz = sW[3072 + kk * 192 + 64 + f];
      float vn = sW[3072 + kk * 192 + 128 + f];
#pragma unroll
      for (int m = 0; m < 8; ++m) {
        float xm = sx[(mb + m) * 64 + k];
        float hm = sh[(mb + m) * 64 + k];
        air[m] = fmaf(xm, wr, air[m]);
        aiz[m] = fmaf(xm, wz, aiz[m]);
        ain[m] = fmaf(xm, wn, ain[m]);
        ahr[m] = fmaf(hm, vr, ahr[m]);
        ahz[m] = fmaf(hm, vz, ahz[m]);
        ahn[m] = fmaf(hm, vn, ahn[m]);
      }
    }
  }

  float hnew[8];
#pragma unroll
  for (int m = 0; m < 8; ++m) {
    float r = sigmoid_f(air[m] + ahr[m]);
    float z = sigmoid_f(aiz[m] + ahz[m]);
    float nn = tanh_f(ain[m] + r * ahn[m]);
    float hold = sh[(mb + m) * 64 + f];
    hnew[m] = (1.f - z) * nn + z * hold;
  }
  __syncthreads();  // all waves past their last sW reads
#pragma unroll
  for (int m = 0; m < 8; ++m) {
    sh[(mb + m) * 64 + f] = hnew[m];  // own-wave rows only; no cross-wave hazard
    int n = node0 + mb + m;
    if (n < N_NODES) h[(size_t)n * 64 + f] = hnew[m];
  }
  // stage WlinT into (now free) sW
  for (int i = tid; i < 64 * 32; i += 512) {
    int k = i >> 5, jj = i & 31;
    sW[i] = Wlin[jj * 64 + k];
  }
  __syncthreads();
  int j = f & 31, hi = f >> 5;
  float o0 = blin[j], o1 = o0, o2 = o0, o3 = o0;
  for (int k = 0; k < 64; ++k) {
    float wv = sW[k * 32 + j];
    o0 = fmaf(sh[(mb + 0 + hi) * 64 + k], wv, o0);
    o1 = fmaf(sh[(mb + 2 + hi) * 64 + k], wv, o1);
    o2 = fmaf(sh[(mb + 4 + hi) * 64 + k], wv, o2);
    o3 = fmaf(sh[(mb + 6 + hi) * 64 + k], wv, o3);
  }
  int n;
  n = node0 + mb + 0 + hi; if (n < N_NODES) outt[(size_t)n * 32 + j] = o0;
  n = node0 + mb + 2 + hi; if (n < N_NODES) outt[(size_t)n * 32 + j] = o1;
  n = node0 + mb + 4 + hi; if (n < N_NODES) outt[(size_t)n * 32 + j] = o2;
  n = node0 + mb + 6 + hi; if (n < N_NODES) outt[(size_t)n * 32 + j] = o3;
}

// ---------------- host launch ----------------

extern "C" void kernel_launch(void* const* d_in, const int* in_sizes, int n_in,
                              void* d_out, int out_size, void* d_ws, size_t ws_size,
                              hipStream_t stream) {
  const float* x    = (const float*)d_in[0];
  const int*   eis  = (const int*)d_in[1];
  const float* ews  = (const float*)d_in[2];
  const float* W1   = (const float*)d_in[3];
  const float* b1   = (const float*)d_in[4];
  const float* W2   = (const float*)d_in[5];
  const float* b2   = (const float*)d_in[6];
  const float* Wih  = (const float*)d_in[7];
  const float* Whh  = (const float*)d_in[8];
  const float* bih  = (const float*)d_in[9];
  const float* bhh  = (const float*)d_in[10];
  const float* Wlin = (const float*)d_in[11];
  const float* blin = (const float*)d_in[12];
  float* out = (float*)d_out;

  char* ws = (char*)d_ws;
  size_t off = 0;
  auto alloc = [&](size_t bytes) { char* p = ws + off; off += (bytes + 255) & ~size_t(255); return p; };
  float* xw1  = (float*)alloc((size_t)N_NODES * 64 * 4);
  float* bufA = (float*)alloc((size_t)N_NODES * 64 * 4);  // h1, then h2 in place
  float* bufB = (float*)alloc((size_t)N_NODES * 64 * 4);  // tanh(embed_t)
  float* hst  = (float*)alloc((size_t)N_NODES * 64 * 4);  // GRU hidden state
  float* degv = (float*)alloc((size_t)N_NODES * 4);       // deg -> dinv in place
  int*   cnt  = (int*)alloc((size_t)N_NODES * 4);
  int*   rp   = (int*)alloc((size_t)(N_NODES + 1) * 4);
  int*   cur  = (int*)alloc((size_t)(N_NODES + 1) * 4);
  int*   sums = (int*)alloc(64 * 4);
  int*   srcs = (int*)alloc((size_t)NE * 4);
  float* nw   = (float*)alloc((size_t)NE * 4);
  if (ws_size < off) return;  // workspace too small: fail loudly in validation

  const int GB_N   = (N_NODES + 255) / 256;   // 391
  const int GB_E   = (NE + 255) / 256;        // 6250
  const int GB_SC  = (N_NODES + 2047) / 2048; // 49
  const int GB_MM  = N_NODES / 32;            // 3125
  const int GB_PR  = N_NODES / 4;             // 25000
  const int GB_GRU = (N_NODES + 63) / 64;     // 1563

  k_xw1<<<GB_MM, 256, 0, stream>>>(x, W1, xw1);

  for (int t = 0; t < T_STEPS; ++t) {
    const int* srcp = eis + (size_t)t * 2 * NE;
    const int* dstp = srcp + NE;
    const float* ewp = ews + (size_t)t * NE;

    k_init<<<GB_N, 256, 0, stream>>>(cnt, degv);
    k_hist<<<GB_E, 256, 0, stream>>>(dstp, ewp, cnt, degv);
    k_dinv<<<GB_N, 256, 0, stream>>>(degv);
    k_scan_a<<<GB_SC, 256, 0, stream>>>(cnt, rp, sums);
    k_scan_c<<<GB_N, 256, 0, stream>>>(rp, sums, cur);
    k_place<<<GB_E, 256, 0, stream>>>(srcp, dstp, ewp, degv, cur, srcs, nw);

    // layer 1: relu(prop(xw1) + b1) -> bufA
    k_prop<<<GB_PR, 256, 0, stream>>>(xw1, rp, srcs, nw, degv, b1, bufA, 0);
    // h2 = h1 @ W2 (in place)
    k_mm64<<<GB_MM, 256, 0, stream>>>(bufA, W2);
    // layer 2 + GRU input activation: tanh(prop(h2) + b2) -> bufB
    k_prop<<<GB_PR, 256, 0, stream>>>(bufA, rp, srcs, nw, degv, b2, bufB, 1);
    // GRU step + fused output linear
    k_gru<<<GB_GRU, 512, 0, stream>>>(bufB, hst, Wih, Whh, bih, bhh, Wlin, blin,
                                      out + (size_t)t * N_NODES * 32, t == 0 ? 1 : 0);
  }
}

// Round 2
// 5021.642 us; speedup vs baseline: 1.2364x; 1.2364x over previous
//
#include <hip/hip_runtime.h>
#include <math.h>

#define N_NODES 100000
#define NE      1600000
#define T_STEPS 8

__device__ __forceinline__ float sigmoid_f(float x) { return 1.f / (1.f + __expf(-x)); }
__device__ __forceinline__ float tanh_f(float x) {
  float e = __expf(2.f * x);
  return 1.f - 2.f / (e + 1.f);
}

// ---------------- per-snapshot CSR build ----------------

__global__ void k_init(int* __restrict__ cnt, float* __restrict__ degv) {
  int i = blockIdx.x * 256 + threadIdx.x;
  if (i < N_NODES) { cnt[i] = 0; degv[i] = 1.0f; }  // deg starts at 1 (self loop w=1)
}

__global__ void k_hist(const int* __restrict__ dst, const float* __restrict__ ew,
                       int* __restrict__ cnt, float* __restrict__ degv) {
  int e = blockIdx.x * 256 + threadIdx.x;
  if (e < NE) {
    int d = dst[e];
    atomicAdd(&cnt[d], 1);
    atomicAdd(&degv[d], ew[e]);
  }
}

__global__ void k_dinv(float* __restrict__ degv) {
  int i = blockIdx.x * 256 + threadIdx.x;
  if (i < N_NODES) degv[i] = rsqrtf(degv[i]);  // deg >= 1 always
}

// chunk = 2048 per block (256 thr x 8). Writes per-chunk exclusive scan, chunk totals to sums.
__global__ void k_scan_a(const int* __restrict__ cnt, int* __restrict__ rp, int* __restrict__ sums) {
  __shared__ int sdata[256];
  int tid = threadIdx.x;
  int base = blockIdx.x * 2048 + tid * 8;
  int v[8];
  int tot = 0;
#pragma unroll
  for (int i = 0; i < 8; ++i) {
    int idx = base + i;
    int c = (idx < N_NODES) ? cnt[idx] : 0;
    v[i] = tot; tot += c;
  }
  sdata[tid] = tot;
  __syncthreads();
  for (int off = 1; off < 256; off <<= 1) {
    int x = (tid >= off) ? sdata[tid - off] : 0;
    __syncthreads();
    sdata[tid] += x;
    __syncthreads();
  }
  int texcl = sdata[tid] - tot;  // exclusive prefix of this thread within chunk
  if (tid == 255) sums[blockIdx.x] = sdata[255];
#pragma unroll
  for (int i = 0; i < 8; ++i) {
    int idx = base + i;
    if (idx < N_NODES) rp[idx] = texcl + v[i];
  }
}

// add chunk bases (computed by summing sums[0..cid-1], only 49 entries), fill cursor.
__global__ void k_scan_c(int* __restrict__ rp, const int* __restrict__ sums, int* __restrict__ cur) {
  __shared__ int sbase;
  int tid = threadIdx.x;
  int cid = blockIdx.x >> 3;  // 256-thread block sits inside one 2048 chunk
  if (tid == 0) {
    int b = 0;
    for (int c = 0; c < cid; ++c) b += sums[c];
    sbase = b;
  }
  __syncthreads();
  int idx = blockIdx.x * 256 + tid;
  if (idx < N_NODES) {
    int vv = rp[idx] + sbase;
    rp[idx] = vv;
    cur[idx] = vv;
  }
  if (blockIdx.x == 0 && tid == 0) rp[N_NODES] = NE;
}

__global__ void k_place(const int* __restrict__ src, const int* __restrict__ dst,
                        const float* __restrict__ ew, const float* __restrict__ dinv,
                        int* __restrict__ cur, int* __restrict__ srcs, float* __restrict__ nw) {
  int e = blockIdx.x * 256 + threadIdx.x;
  if (e < NE) {
    int s = src[e], d = dst[e];
    float w = ew[e];
    int p = atomicAdd(&cur[d], 1);
    srcs[p] = s;
    nw[p] = dinv[s] * w * dinv[d];
  }
}

// ---------------- GCN propagation: one wave per node, lane = feature ----------------

__global__ void k_prop(const float* __restrict__ hin, const int* __restrict__ rp,
                       const int* __restrict__ srcs, const float* __restrict__ nw,
                       const float* __restrict__ dinv, const float* __restrict__ bias,
                       float* __restrict__ hout, int mode /*0=relu, 1=tanh*/) {
  int node = blockIdx.x * 4 + (threadIdx.x >> 6);
  int f = threadIdx.x & 63;
  float di = dinv[node];
  float acc = hin[(size_t)node * 64 + f] * di * di;  // self loop: norm = dinv^2
  int e0 = rp[node], e1 = rp[node + 1];
  float a0 = 0.f, a1 = 0.f, a2 = 0.f, a3 = 0.f;
  int j = e0;
  for (; j + 4 <= e1; j += 4) {
    int s0 = srcs[j], s1 = srcs[j + 1], s2 = srcs[j + 2], s3 = srcs[j + 3];
    float w0 = nw[j], w1 = nw[j + 1], w2 = nw[j + 2], w3 = nw[j + 3];
    a0 = fmaf(hin[(size_t)s0 * 64 + f], w0, a0);
    a1 = fmaf(hin[(size_t)s1 * 64 + f], w1, a1);
    a2 = fmaf(hin[(size_t)s2 * 64 + f], w2, a2);
    a3 = fmaf(hin[(size_t)s3 * 64 + f], w3, a3);
  }
  for (; j < e1; ++j) acc = fmaf(hin[(size_t)srcs[j] * 64 + f], nw[j], acc);
  acc += (a0 + a1) + (a2 + a3);
  acc += bias[f];
  hout[(size_t)node * 64 + f] = (mode == 0) ? fmaxf(acc, 0.f) : tanh_f(acc);
}

// ---------------- dense matmuls ----------------

// xw1 = x @ W1 : [N,128]@[128,64]
__global__ void k_xw1(const float* __restrict__ x, const float* __restrict__ W1, float* __restrict__ o) {
  __shared__ float sW[128 * 64];   // 32 KB
  __shared__ float sx[32 * 128];   // 16 KB
  int tid = threadIdx.x;
  int row0 = blockIdx.x * 32;
  for (int i = tid; i < 128 * 64; i += 256) sW[i] = W1[i];
  for (int i = tid; i < 32 * 128; i += 256) {
    int r = i >> 7, c = i & 127;
    sx[i] = x[(size_t)(row0 + r) * 128 + c];
  }
  __syncthreads();
  int f = tid & 63, w = tid >> 6;
  float acc[8];
#pragma unroll
  for (int m = 0; m < 8; ++m) acc[m] = 0.f;
  for (int k = 0; k < 128; ++k) {
    float wv = sW[k * 64 + f];
#pragma unroll
    for (int m = 0; m < 8; ++m)
      acc[m] = fmaf(sx[(w * 8 + m) * 128 + k], wv, acc[m]);
  }
#pragma unroll
  for (int m = 0; m < 8; ++m)
    o[(size_t)(row0 + w * 8 + m) * 64 + f] = acc[m];
}

// a = a @ W2 in place : [N,64]@[64,64] (rows staged to LDS first, so in-place is safe)
__global__ void k_mm64(float* __restrict__ a, const float* __restrict__ W2) {
  __shared__ float sW[64 * 64];   // 16 KB
  __shared__ float sx[32 * 64];   // 8 KB
  int tid = threadIdx.x;
  int row0 = blockIdx.x * 32;
  for (int i = tid; i < 64 * 64; i += 256) sW[i] = W2[i];
  for (int i = tid; i < 32 * 64; i += 256) {
    int r = i >> 6, c = i & 63;
    sx[i] = a[(size_t)(row0 + r) * 64 + c];
  }
  __syncthreads();
  int f = tid & 63, w = tid >> 6;
  float acc[8];
#pragma unroll
  for (int m = 0; m < 8; ++m) acc[m] = 0.f;
  for (int k = 0; k < 64; ++k) {
    float wv = sW[k * 64 + f];
#pragma unroll
    for (int m = 0; m < 8; ++m)
      acc[m] = fmaf(sx[(w * 8 + m) * 64 + k], wv, acc[m]);
  }
#pragma unroll
  for (int m = 0; m < 8; ++m)
    a[(size_t)(row0 + w * 8 + m) * 64 + f] = acc[m];
}

// ---------------- fused GRU step + output linear ----------------
// 512 threads = 8 waves, 4 nodes/wave, 32 nodes/block (100000 = 32*3125 exactly).
// 24 accumulators/thread -> no spills (round-1 k_gru spilled ~300 MB of scratch).
// Weight k-tile restaged gate-interleaved+padded: sW[kk*260 + f*4 + g] so each
// lane reads its 3 gate weights as one ds_read_b128 (contiguous 1 KB/wave).
#define WPAD 260  // 260 % 32 == 4 -> staging writes spread across banks; rows stay 16B aligned
__global__ __launch_bounds__(512, 2) void k_gru(
    const float* __restrict__ gt, float* __restrict__ h,
    const float* __restrict__ Wih, const float* __restrict__ Whh,
    const float* __restrict__ bih, const float* __restrict__ bhh,
    const float* __restrict__ Wlin, const float* __restrict__ blin,
    float* __restrict__ outt, int first) {
  __shared__ float sWi[16 * WPAD];  // 16.25 KB (k-tile of Wih, gate-interleaved)
  __shared__ float sWh[16 * WPAD];  // 16.25 KB
  __shared__ float sx[32 * 64];     // 8 KB
  __shared__ float sh[32 * 64];     // 8 KB

  int tid = threadIdx.x;
  int node0 = blockIdx.x * 32;

  for (int i = tid; i < 32 * 64; i += 512) {
    sx[i] = gt[(size_t)node0 * 64 + i];
    sh[i] = first ? 0.f : h[(size_t)node0 * 64 + i];
  }

  int f = tid & 63;
  int w = tid >> 6;
  int mb = w * 4;

  float air[4] = {0, 0, 0, 0}, aiz[4] = {0, 0, 0, 0}, ain[4] = {0, 0, 0, 0};
  float ahr[4] = {0, 0, 0, 0}, ahz[4] = {0, 0, 0, 0}, ahn[4] = {0, 0, 0, 0};

  for (int kt = 0; kt < 64; kt += 16) {
    __syncthreads();  // prior tile reads done (also covers initial sx/sh staging)
    // stage k-tile: i enumerates (jj 0..191, kk 0..15); consecutive tid -> consecutive kk
    for (int i = tid; i < 192 * 16; i += 512) {
      int kk = i & 15, jj = i >> 4;
      int g = jj >> 6, ff = jj & 63;
      sWi[kk * WPAD + ff * 4 + g] = Wih[jj * 64 + kt + kk];
      sWh[kk * WPAD + ff * 4 + g] = Whh[jj * 64 + kt + kk];
    }
    __syncthreads();
#pragma unroll
    for (int kk = 0; kk < 16; ++kk) {
      int k = kt + kk;
      float4 wi = *reinterpret_cast<const float4*>(&sWi[kk * WPAD + f * 4]);
      float4 wh = *reinterpret_cast<const float4*>(&sWh[kk * WPAD + f * 4]);
#pragma unroll
      for (int m = 0; m < 4; ++m) {
        float xm = sx[(mb + m) * 64 + k];
        float hm = sh[(mb + m) * 64 + k];
        air[m] = fmaf(xm, wi.x, air[m]);
        aiz[m] = fmaf(xm, wi.y, aiz[m]);
        ain[m] = fmaf(xm, wi.z, ain[m]);
        ahr[m] = fmaf(hm, wh.x, ahr[m]);
        ahz[m] = fmaf(hm, wh.y, ahz[m]);
        ahn[m] = fmaf(hm, wh.z, ahn[m]);
      }
    }
  }

  float bir = bih[f], biz = bih[64 + f], bin = bih[128 + f];
  float bhr = bhh[f], bhz = bhh[64 + f], bhn = bhh[128 + f];

  float hnew[4];
#pragma unroll
  for (int m = 0; m < 4; ++m) {
    float r = sigmoid_f(air[m] + bir + ahr[m] + bhr);
    float z = sigmoid_f(aiz[m] + biz + ahz[m] + bhz);
    float nn = tanh_f(ain[m] + bin + r * (ahn[m] + bhn));
    float hold = sh[(mb + m) * 64 + f];  // own-wave row, safe
    hnew[m] = (1.f - z) * nn + z * hold;
  }
#pragma unroll
  for (int m = 0; m < 4; ++m) {
    sh[(mb + m) * 64 + f] = hnew[m];  // own-wave rows only; no cross-wave hazard
    h[(size_t)(node0 + mb + m) * 64 + f] = hnew[m];
  }

  __syncthreads();  // all waves done reading sWi before reuse for WlinT
  for (int i = tid; i < 64 * 32; i += 512) {
    int k = i >> 5, jj = i & 31;
    sWi[k * 32 + jj] = Wlin[jj * 64 + k];
  }
  __syncthreads();

  int j = f & 31, hi = f >> 5;
  float o0 = blin[j], o1 = o0;
  for (int k = 0; k < 64; ++k) {
    float wv = sWi[k * 32 + j];
    o0 = fmaf(sh[(mb + 0 + hi) * 64 + k], wv, o0);
    o1 = fmaf(sh[(mb + 2 + hi) * 64 + k], wv, o1);
  }
  outt[(size_t)(node0 + mb + 0 + hi) * 32 + j] = o0;
  outt[(size_t)(node0 + mb + 2 + hi) * 32 + j] = o1;
}

// ---------------- host launch ----------------

extern "C" void kernel_launch(void* const* d_in, const int* in_sizes, int n_in,
                              void* d_out, int out_size, void* d_ws, size_t ws_size,
                              hipStream_t stream) {
  const float* x    = (const float*)d_in[0];
  const int*   eis  = (const int*)d_in[1];
  const float* ews  = (const float*)d_in[2];
  const float* W1   = (const float*)d_in[3];
  const float* b1   = (const float*)d_in[4];
  const float* W2   = (const float*)d_in[5];
  const float* b2   = (const float*)d_in[6];
  const float* Wih  = (const float*)d_in[7];
  const float* Whh  = (const float*)d_in[8];
  const float* bih  = (const float*)d_in[9];
  const float* bhh  = (const float*)d_in[10];
  const float* Wlin = (const float*)d_in[11];
  const float* blin = (const float*)d_in[12];
  float* out = (float*)d_out;

  char* ws = (char*)d_ws;
  size_t off = 0;
  auto alloc = [&](size_t bytes) { char* p = ws + off; off += (bytes + 255) & ~size_t(255); return p; };
  float* xw1  = (float*)alloc((size_t)N_NODES * 64 * 4);
  float* bufA = (float*)alloc((size_t)N_NODES * 64 * 4);  // h1, then h2 in place
  float* bufB = (float*)alloc((size_t)N_NODES * 64 * 4);  // tanh(embed_t)
  float* hst  = (float*)alloc((size_t)N_NODES * 64 * 4);  // GRU hidden state
  float* degv = (float*)alloc((size_t)N_NODES * 4);       // deg -> dinv in place
  int*   cnt  = (int*)alloc((size_t)N_NODES * 4);
  int*   rp   = (int*)alloc((size_t)(N_NODES + 1) * 4);
  int*   cur  = (int*)alloc((size_t)(N_NODES + 1) * 4);
  int*   sums = (int*)alloc(64 * 4);
  int*   srcs = (int*)alloc((size_t)NE * 4);
  float* nw   = (float*)alloc((size_t)NE * 4);
  if (ws_size < off) return;  // workspace too small: fail loudly in validation

  const int GB_N   = (N_NODES + 255) / 256;   // 391
  const int GB_E   = (NE + 255) / 256;        // 6250
  const int GB_SC  = (N_NODES + 2047) / 2048; // 49
  const int GB_MM  = N_NODES / 32;            // 3125
  const int GB_PR  = N_NODES / 4;             // 25000
  const int GB_GRU = N_NODES / 32;            // 3125

  k_xw1<<<GB_MM, 256, 0, stream>>>(x, W1, xw1);

  for (int t = 0; t < T_STEPS; ++t) {
    const int* srcp = eis + (size_t)t * 2 * NE;
    const int* dstp = srcp + NE;
    const float* ewp = ews + (size_t)t * NE;

    k_init<<<GB_N, 256, 0, stream>>>(cnt, degv);
    k_hist<<<GB_E, 256, 0, stream>>>(dstp, ewp, cnt, degv);
    k_dinv<<<GB_N, 256, 0, stream>>>(degv);
    k_scan_a<<<GB_SC, 256, 0, stream>>>(cnt, rp, sums);
    k_scan_c<<<GB_N, 256, 0, stream>>>(rp, sums, cur);
    k_place<<<GB_E, 256, 0, stream>>>(srcp, dstp, ewp, degv, cur, srcs, nw);

    // layer 1: relu(prop(xw1) + b1) -> bufA
    k_prop<<<GB_PR, 256, 0, stream>>>(xw1, rp, srcs, nw, degv, b1, bufA, 0);
    // h2 = h1 @ W2 (in place)
    k_mm64<<<GB_MM, 256, 0, stream>>>(bufA, W2);
    // layer 2 + GRU input activation: tanh(prop(h2) + b2) -> bufB
    k_prop<<<GB_PR, 256, 0, stream>>>(bufA, rp, srcs, nw, degv, b2, bufB, 1);
    // GRU step + fused output linear
    k_gru<<<GB_GRU, 512, 0, stream>>>(bufB, hst, Wih, Whh, bih, bhh, Wlin, blin,
                                      out + (size_t)t * N_NODES * 32, t == 0 ? 1 : 0);
  }
}

// Round 3
// 4810.180 us; speedup vs baseline: 1.2907x; 1.0440x over previous
//
#include <hip/hip_runtime.h>
#include <math.h>

#define N_NODES 100000
#define NE      1600000
#define T_STEPS 8

__device__ __forceinline__ float sigmoid_f(float x) { return 1.f / (1.f + __expf(-x)); }
__device__ __forceinline__ float tanh_f(float x) {
  float e = __expf(2.f * x);
  return 1.f - 2.f / (e + 1.f);
}

// ---------------- per-snapshot CSR build ----------------

__global__ void k_init(int* __restrict__ cnt, float* __restrict__ degv) {
  int i = blockIdx.x * 256 + threadIdx.x;
  if (i < N_NODES) { cnt[i] = 0; degv[i] = 1.0f; }  // deg starts at 1 (self loop w=1)
}

__global__ void k_hist(const int* __restrict__ dst, const float* __restrict__ ew,
                       int* __restrict__ cnt, float* __restrict__ degv) {
  int e = blockIdx.x * 256 + threadIdx.x;
  if (e < NE) {
    int d = dst[e];
    atomicAdd(&cnt[d], 1);
    atomicAdd(&degv[d], ew[e]);
  }
}

// chunk = 2048 per block (256 thr x 8). Writes per-chunk exclusive scan, chunk totals to sums.
__global__ void k_scan_a(const int* __restrict__ cnt, int* __restrict__ rp, int* __restrict__ sums) {
  __shared__ int sdata[256];
  int tid = threadIdx.x;
  int base = blockIdx.x * 2048 + tid * 8;
  int v[8];
  int tot = 0;
#pragma unroll
  for (int i = 0; i < 8; ++i) {
    int idx = base + i;
    int c = (idx < N_NODES) ? cnt[idx] : 0;
    v[i] = tot; tot += c;
  }
  sdata[tid] = tot;
  __syncthreads();
  for (int off = 1; off < 256; off <<= 1) {
    int x = (tid >= off) ? sdata[tid - off] : 0;
    __syncthreads();
    sdata[tid] += x;
    __syncthreads();
  }
  int texcl = sdata[tid] - tot;  // exclusive prefix of this thread within chunk
  if (tid == 255) sums[blockIdx.x] = sdata[255];
#pragma unroll
  for (int i = 0; i < 8; ++i) {
    int idx = base + i;
    if (idx < N_NODES) rp[idx] = texcl + v[i];
  }
}

// add chunk bases, fill cursor, and finalize dinv = rsqrt(deg) (folded-in k_dinv).
__global__ void k_scan_c(int* __restrict__ rp, const int* __restrict__ sums, int* __restrict__ cur,
                         float* __restrict__ degv) {
  __shared__ int sbase;
  int tid = threadIdx.x;
  int cid = blockIdx.x >> 3;  // 256-thread block sits inside one 2048 chunk
  if (tid == 0) {
    int b = 0;
    for (int c = 0; c < cid; ++c) b += sums[c];
    sbase = b;
  }
  __syncthreads();
  int idx = blockIdx.x * 256 + tid;
  if (idx < N_NODES) {
    int vv = rp[idx] + sbase;
    rp[idx] = vv;
    cur[idx] = vv;
    degv[idx] = rsqrtf(degv[idx]);  // deg >= 1 always
  }
  if (blockIdx.x == 0 && tid == 0) rp[N_NODES] = NE;
}

__global__ void k_place(const int* __restrict__ src, const int* __restrict__ dst,
                        const float* __restrict__ ew, const float* __restrict__ dinv,
                        int* __restrict__ cur, int* __restrict__ srcs, float* __restrict__ nw) {
  int e = blockIdx.x * 256 + threadIdx.x;
  if (e < NE) {
    int s = src[e], d = dst[e];
    float w = ew[e];
    int p = atomicAdd(&cur[d], 1);
    srcs[p] = s;
    nw[p] = dinv[s] * w * dinv[d];
  }
}

// ---------------- GCN propagation: one wave per node, lane = feature ----------------

__global__ void k_prop(const float* __restrict__ hin, const int* __restrict__ rp,
                       const int* __restrict__ srcs, const float* __restrict__ nw,
                       const float* __restrict__ dinv, const float* __restrict__ bias,
                       float* __restrict__ hout, int mode /*0=relu, 1=tanh*/) {
  int node = blockIdx.x * 4 + (threadIdx.x >> 6);
  int f = threadIdx.x & 63;
  float di = dinv[node];
  float acc = hin[(size_t)node * 64 + f] * di * di;  // self loop: norm = dinv^2
  int e0 = rp[node], e1 = rp[node + 1];
  float a0 = 0.f, a1 = 0.f, a2 = 0.f, a3 = 0.f;
  int j = e0;
  for (; j + 4 <= e1; j += 4) {
    int s0 = srcs[j], s1 = srcs[j + 1], s2 = srcs[j + 2], s3 = srcs[j + 3];
    float w0 = nw[j], w1 = nw[j + 1], w2 = nw[j + 2], w3 = nw[j + 3];
    a0 = fmaf(hin[(size_t)s0 * 64 + f], w0, a0);
    a1 = fmaf(hin[(size_t)s1 * 64 + f], w1, a1);
    a2 = fmaf(hin[(size_t)s2 * 64 + f], w2, a2);
    a3 = fmaf(hin[(size_t)s3 * 64 + f], w3, a3);
  }
  for (; j < e1; ++j) acc = fmaf(hin[(size_t)srcs[j] * 64 + f], nw[j], acc);
  acc += (a0 + a1) + (a2 + a3);
  acc += bias[f];
  hout[(size_t)node * 64 + f] = (mode == 0) ? fmaxf(acc, 0.f) : tanh_f(acc);
}

// ---------------- dense matmuls ----------------

// xw1 = x @ W1 : [N,128]@[128,64]
__global__ void k_xw1(const float* __restrict__ x, const float* __restrict__ W1, float* __restrict__ o) {
  __shared__ float sW[128 * 64];   // 32 KB
  __shared__ float sx[32 * 128];   // 16 KB
  int tid = threadIdx.x;
  int row0 = blockIdx.x * 32;
  for (int i = tid; i < 128 * 64; i += 256) sW[i] = W1[i];
  for (int i = tid; i < 32 * 128; i += 256) {
    int r = i >> 7, c = i & 127;
    sx[i] = x[(size_t)(row0 + r) * 128 + c];
  }
  __syncthreads();
  int f = tid & 63, w = tid >> 6;
  float acc[8];
#pragma unroll
  for (int m = 0; m < 8; ++m) acc[m] = 0.f;
  for (int k = 0; k < 128; ++k) {
    float wv = sW[k * 64 + f];
#pragma unroll
    for (int m = 0; m < 8; ++m)
      acc[m] = fmaf(sx[(w * 8 + m) * 128 + k], wv, acc[m]);
  }
#pragma unroll
  for (int m = 0; m < 8; ++m)
    o[(size_t)(row0 + w * 8 + m) * 64 + f] = acc[m];
}

// a = a @ W2 in place : [N,64]@[64,64] (rows staged to LDS first, so in-place is safe)
__global__ void k_mm64(float* __restrict__ a, const float* __restrict__ W2) {
  __shared__ float sW[64 * 64];   // 16 KB
  __shared__ float sx[32 * 64];   // 8 KB
  int tid = threadIdx.x;
  int row0 = blockIdx.x * 32;
  for (int i = tid; i < 64 * 64; i += 256) sW[i] = W2[i];
  for (int i = tid; i < 32 * 64; i += 256) {
    int r = i >> 6, c = i & 63;
    sx[i] = a[(size_t)(row0 + r) * 64 + c];
  }
  __syncthreads();
  int f = tid & 63, w = tid >> 6;
  float acc[8];
#pragma unroll
  for (int m = 0; m < 8; ++m) acc[m] = 0.f;
  for (int k = 0; k < 64; ++k) {
    float wv = sW[k * 64 + f];
#pragma unroll
    for (int m = 0; m < 8; ++m)
      acc[m] = fmaf(sx[(w * 8 + m) * 64 + k], wv, acc[m]);
  }
#pragma unroll
  for (int m = 0; m < 8; ++m)
    a[(size_t)(row0 + w * 8 + m) * 64 + f] = acc[m];
}

// ---------------- fused GRU step + output linear ----------------
// 256 threads = 4 waves, 8 nodes/wave, 32 nodes/block (100000 = 32*3125 exactly).
// Round-2 was LDS-pipe-bound (7.2M conflict cycles, VALUBusy 50%): ~70 LDS cyc vs
// 48 VALU cyc per wave-kk. Now: k processed in groups of 4; x/h read as wave-uniform
// broadcast float4 (free), weights as ds_read_b128; m=8 doubles FMAs per weight read.
// LDS cyc/FMA ~1.0 vs VALU 2.0 -> VALU-bound.
#define WPAD 264  // words; 264%32==8 spreads staging banks; rows 16B-aligned (264*4=1056)
__global__ __launch_bounds__(256, 3) void k_gru(
    const float* __restrict__ gt, float* __restrict__ h,
    const float* __restrict__ Wih, const float* __restrict__ Whh,
    const float* __restrict__ bih, const float* __restrict__ bhh,
    const float* __restrict__ Wlin, const float* __restrict__ blin,
    float* __restrict__ outt, int first) {
  __shared__ float sWi[8 * WPAD];   // 8448 B (k-tile of Wih, gate-interleaved)
  __shared__ float sWh[8 * WPAD];   // 8448 B
  __shared__ float sx[32 * 64];     // 16 KB
  __shared__ float sh[32 * 64];     // 16 KB
  // total 49664 B -> 3 blocks/CU

  int tid = threadIdx.x;
  int node0 = blockIdx.x * 32;

  for (int i = tid; i < 32 * 64; i += 256) {
    sx[i] = gt[(size_t)node0 * 64 + i];
    sh[i] = first ? 0.f : h[(size_t)node0 * 64 + i];
  }

  int f = tid & 63;
  int w = tid >> 6;   // 0..3
  int mb = w * 8;

  float air[8], aiz[8], ain[8], ahr[8], ahz[8], ahn[8];
#pragma unroll
  for (int m = 0; m < 8; ++m) { air[m]=0.f; aiz[m]=0.f; ain[m]=0.f; ahr[m]=0.f; ahz[m]=0.f; ahn[m]=0.f; }

  for (int kt = 0; kt < 64; kt += 8) {
    __syncthreads();  // prior tile reads done (also covers initial sx/sh staging)
    // stage k-tile of 8: 192*8 = 1536 elems per buffer, 6 iters
    for (int i = tid; i < 192 * 8; i += 256) {
      int kk = i & 7, jj = i >> 3;
      int g = jj >> 6, ff = jj & 63;
      sWi[kk * WPAD + ff * 4 + g] = Wih[jj * 64 + kt + kk];
      sWh[kk * WPAD + ff * 4 + g] = Whh[jj * 64 + kt + kk];
    }
    __syncthreads();
#pragma unroll
    for (int kg = 0; kg < 8; kg += 4) {
      float4 wi0 = *reinterpret_cast<const float4*>(&sWi[(kg + 0) * WPAD + f * 4]);
      float4 wi1 = *reinterpret_cast<const float4*>(&sWi[(kg + 1) * WPAD + f * 4]);
      float4 wi2 = *reinterpret_cast<const float4*>(&sWi[(kg + 2) * WPAD + f * 4]);
      float4 wi3 = *reinterpret_cast<const float4*>(&sWi[(kg + 3) * WPAD + f * 4]);
      float4 wh0 = *reinterpret_cast<const float4*>(&sWh[(kg + 0) * WPAD + f * 4]);
      float4 wh1 = *reinterpret_cast<const float4*>(&sWh[(kg + 1) * WPAD + f * 4]);
      float4 wh2 = *reinterpret_cast<const float4*>(&sWh[(kg + 2) * WPAD + f * 4]);
      float4 wh3 = *reinterpret_cast<const float4*>(&sWh[(kg + 3) * WPAD + f * 4]);
#pragma unroll
      for (int m = 0; m < 8; ++m) {
        float4 xm = *reinterpret_cast<const float4*>(&sx[(mb + m) * 64 + kt + kg]);  // broadcast
        float4 hm = *reinterpret_cast<const float4*>(&sh[(mb + m) * 64 + kt + kg]);  // broadcast
        air[m] = fmaf(xm.x, wi0.x, air[m]); aiz[m] = fmaf(xm.x, wi0.y, aiz[m]); ain[m] = fmaf(xm.x, wi0.z, ain[m]);
        ahr[m] = fmaf(hm.x, wh0.x, ahr[m]); ahz[m] = fmaf(hm.x, wh0.y, ahz[m]); ahn[m] = fmaf(hm.x, wh0.z, ahn[m]);
        air[m] = fmaf(xm.y, wi1.x, air[m]); aiz[m] = fmaf(xm.y, wi1.y, aiz[m]); ain[m] = fmaf(xm.y, wi1.z, ain[m]);
        ahr[m] = fmaf(hm.y, wh1.x, ahr[m]); ahz[m] = fmaf(hm.y, wh1.y, ahz[m]); ahn[m] = fmaf(hm.y, wh1.z, ahn[m]);
        air[m] = fmaf(xm.z, wi2.x, air[m]); aiz[m] = fmaf(xm.z, wi2.y, aiz[m]); ain[m] = fmaf(xm.z, wi2.z, ain[m]);
        ahr[m] = fmaf(hm.z, wh2.x, ahr[m]); ahz[m] = fmaf(hm.z, wh2.y, ahz[m]); ahn[m] = fmaf(hm.z, wh2.z, ahn[m]);
        air[m] = fmaf(xm.w, wi3.x, air[m]); aiz[m] = fmaf(xm.w, wi3.y, aiz[m]); ain[m] = fmaf(xm.w, wi3.z, ain[m]);
        ahr[m] = fmaf(hm.w, wh3.x, ahr[m]); ahz[m] = fmaf(hm.w, wh3.y, ahz[m]); ahn[m] = fmaf(hm.w, wh3.z, ahn[m]);
      }
    }
  }

  float bir = bih[f], biz = bih[64 + f], bin = bih[128 + f];
  float bhr = bhh[f], bhz = bhh[64 + f], bhn = bhh[128 + f];

  float hnew[8];
#pragma unroll
  for (int m = 0; m < 8; ++m) {
    float r = sigmoid_f(air[m] + bir + ahr[m] + bhr);
    float z = sigmoid_f(aiz[m] + biz + ahz[m] + bhz);
    float nn = tanh_f(ain[m] + bin + r * (ahn[m] + bhn));
    float hold = sh[(mb + m) * 64 + f];  // own-wave row, safe
    hnew[m] = (1.f - z) * nn + z * hold;
  }
#pragma unroll
  for (int m = 0; m < 8; ++m) {
    sh[(mb + m) * 64 + f] = hnew[m];  // own-wave rows only; no cross-wave hazard
    h[(size_t)(node0 + mb + m) * 64 + f] = hnew[m];
  }

  __syncthreads();  // all waves done reading sWi before reuse for WlinT
  for (int i = tid; i < 64 * 32; i += 256) {
    int k = i >> 5, jj = i & 31;
    sWi[k * 32 + jj] = Wlin[jj * 64 + k];
  }
  __syncthreads();

  int j = f & 31, hi = f >> 5;
  float o0 = blin[j], o1 = o0, o2 = o0, o3 = o0;
  for (int k = 0; k < 64; ++k) {
    float wv = sWi[k * 32 + j];
    o0 = fmaf(sh[(mb + 0 + hi) * 64 + k], wv, o0);
    o1 = fmaf(sh[(mb + 2 + hi) * 64 + k], wv, o1);
    o2 = fmaf(sh[(mb + 4 + hi) * 64 + k], wv, o2);
    o3 = fmaf(sh[(mb + 6 + hi) * 64 + k], wv, o3);
  }
  outt[(size_t)(node0 + mb + 0 + hi) * 32 + j] = o0;
  outt[(size_t)(node0 + mb + 2 + hi) * 32 + j] = o1;
  outt[(size_t)(node0 + mb + 4 + hi) * 32 + j] = o2;
  outt[(size_t)(node0 + mb + 6 + hi) * 32 + j] = o3;
}

// ---------------- host launch ----------------

extern "C" void kernel_launch(void* const* d_in, const int* in_sizes, int n_in,
                              void* d_out, int out_size, void* d_ws, size_t ws_size,
                              hipStream_t stream) {
  const float* x    = (const float*)d_in[0];
  const int*   eis  = (const int*)d_in[1];
  const float* ews  = (const float*)d_in[2];
  const float* W1   = (const float*)d_in[3];
  const float* b1   = (const float*)d_in[4];
  const float* W2   = (const float*)d_in[5];
  const float* b2   = (const float*)d_in[6];
  const float* Wih  = (const float*)d_in[7];
  const float* Whh  = (const float*)d_in[8];
  const float* bih  = (const float*)d_in[9];
  const float* bhh  = (const float*)d_in[10];
  const float* Wlin = (const float*)d_in[11];
  const float* blin = (const float*)d_in[12];
  float* out = (float*)d_out;

  char* ws = (char*)d_ws;
  size_t off = 0;
  auto alloc = [&](size_t bytes) { char* p = ws + off; off += (bytes + 255) & ~size_t(255); return p; };
  float* xw1  = (float*)alloc((size_t)N_NODES * 64 * 4);
  float* bufA = (float*)alloc((size_t)N_NODES * 64 * 4);  // h1, then h2 in place
  float* bufB = (float*)alloc((size_t)N_NODES * 64 * 4);  // tanh(embed_t)
  float* hst  = (float*)alloc((size_t)N_NODES * 64 * 4);  // GRU hidden state
  float* degv = (float*)alloc((size_t)N_NODES * 4);       // deg -> dinv in place
  int*   cnt  = (int*)alloc((size_t)N_NODES * 4);
  int*   rp   = (int*)alloc((size_t)(N_NODES + 1) * 4);
  int*   cur  = (int*)alloc((size_t)(N_NODES + 1) * 4);
  int*   sums = (int*)alloc(64 * 4);
  int*   srcs = (int*)alloc((size_t)NE * 4);
  float* nw   = (float*)alloc((size_t)NE * 4);
  if (ws_size < off) return;  // workspace too small: fail loudly in validation

  const int GB_N   = (N_NODES + 255) / 256;   // 391
  const int GB_E   = (NE + 255) / 256;        // 6250
  const int GB_SC  = (N_NODES + 2047) / 2048; // 49
  const int GB_MM  = N_NODES / 32;            // 3125
  const int GB_PR  = N_NODES / 4;             // 25000
  const int GB_GRU = N_NODES / 32;            // 3125

  k_xw1<<<GB_MM, 256, 0, stream>>>(x, W1, xw1);

  for (int t = 0; t < T_STEPS; ++t) {
    const int* srcp = eis + (size_t)t * 2 * NE;
    const int* dstp = srcp + NE;
    const float* ewp = ews + (size_t)t * NE;

    k_init<<<GB_N, 256, 0, stream>>>(cnt, degv);
    k_hist<<<GB_E, 256, 0, stream>>>(dstp, ewp, cnt, degv);
    k_scan_a<<<GB_SC, 256, 0, stream>>>(cnt, rp, sums);
    k_scan_c<<<GB_N, 256, 0, stream>>>(rp, sums, cur, degv);
    k_place<<<GB_E, 256, 0, stream>>>(srcp, dstp, ewp, degv, cur, srcs, nw);

    // layer 1: relu(prop(xw1) + b1) -> bufA
    k_prop<<<GB_PR, 256, 0, stream>>>(xw1, rp, srcs, nw, degv, b1, bufA, 0);
    // h2 = h1 @ W2 (in place)
    k_mm64<<<GB_MM, 256, 0, stream>>>(bufA, W2);
    // layer 2 + GRU input activation: tanh(prop(h2) + b2) -> bufB
    k_prop<<<GB_PR, 256, 0, stream>>>(bufA, rp, srcs, nw, degv, b2, bufB, 1);
    // GRU step + fused output linear
    k_gru<<<GB_GRU, 256, 0, stream>>>(bufB, hst, Wih, Whh, bih, bhh, Wlin, blin,
                                      out + (size_t)t * N_NODES * 32, t == 0 ? 1 : 0);
  }
}